// Round 1
// baseline (1181.087 us; speedup 1.0000x reference)
//
#include <hip/hip_runtime.h>

#define HF 96
#define C4 24          // float4 chunks per row
#define NGRAPHS 500
#define EPS 1e-5f

// ---------------- CSR build ----------------

__global__ void count_kernel(const int* __restrict__ dst, int E, int* __restrict__ cnt) {
    int stride = gridDim.x * blockDim.x;
    for (int i = blockIdx.x * blockDim.x + threadIdx.x; i < E; i += stride)
        atomicAdd(&cnt[dst[i]], 1);
}

__global__ void node_init_kernel(const int* __restrict__ cnt, const int* __restrict__ batch,
                                 int N, float* __restrict__ dinv, float* __restrict__ selfw,
                                 int* __restrict__ gcnt) {
    int stride = gridDim.x * blockDim.x;
    for (int i = blockIdx.x * blockDim.x + threadIdx.x; i < N; i += stride) {
        float d = (float)(cnt[i] + 1);      // +1 self loop
        dinv[i] = 1.0f / sqrtf(d);
        selfw[i] = 1.0f / d;
        atomicAdd(&gcnt[batch[i]], 1);
    }
}

__global__ void scan_kernel(int* __restrict__ cnt, int* __restrict__ row_ptr, int N) {
    __shared__ int sums[1024];
    int t = threadIdx.x;
    int per = (N + 1023) / 1024;
    int lo = min(t * per, N), hi = min(lo + per, N);
    int s = 0;
    for (int i = lo; i < hi; ++i) s += cnt[i];
    sums[t] = s;
    __syncthreads();
    for (int off = 1; off < 1024; off <<= 1) {
        int v = (t >= off) ? sums[t - off] : 0;
        __syncthreads();
        sums[t] += v;
        __syncthreads();
    }
    int base = (t == 0) ? 0 : sums[t - 1];
    for (int i = lo; i < hi; ++i) {
        int c = cnt[i];
        row_ptr[i] = base;
        base += c;
        cnt[i] = 0;                          // re-zero for scatter phase
    }
    if (t == 1023) row_ptr[N] = sums[1023];
}

__global__ void scatter_kernel(const int* __restrict__ src, const int* __restrict__ dst, int E,
                               const int* __restrict__ row_ptr, int* __restrict__ cnt,
                               const float* __restrict__ dinv,
                               int* __restrict__ csr_src, float* __restrict__ csr_w) {
    int stride = gridDim.x * blockDim.x;
    for (int i = blockIdx.x * blockDim.x + threadIdx.x; i < E; i += stride) {
        int d = dst[i], s = src[i];
        int p = row_ptr[d] + atomicAdd(&cnt[d], 1);
        csr_src[p] = s;
        csr_w[p] = dinv[s] * dinv[d];
    }
}

// ---------------- per-layer: matmul (with fused BN+ReLU of previous layer) ----------------

__global__ __launch_bounds__(256) void
matmul_kernel(const float* __restrict__ in, const float* __restrict__ W,
              float* __restrict__ out, int N, int applyBN,
              const double* __restrict__ bnsum,
              const float* __restrict__ bnG, const float* __restrict__ bnB) {
    __shared__ float4 sW[HF * C4];           // 36 KB: W[k][4c..4c+3]
    __shared__ float4 sAl[C4], sBe[C4];
    for (int i = threadIdx.x; i < HF * C4; i += blockDim.x)
        sW[i] = ((const float4*)W)[i];
    if (threadIdx.x < HF) {
        float a = 1.f, b = 0.f;
        if (applyBN) {
            double invN = 1.0 / (double)N;
            double mu = bnsum[threadIdx.x] * invN;
            double var = bnsum[HF + threadIdx.x] * invN - mu * mu;
            float v = fmaxf((float)var, 0.f) + EPS;
            a = bnG[threadIdx.x] / sqrtf(v);
            b = bnB[threadIdx.x] - (float)mu * a;
        }
        ((float*)sAl)[threadIdx.x] = a;
        ((float*)sBe)[threadIdx.x] = b;
    }
    __syncthreads();
    int total = N * C4;
    int stride = gridDim.x * blockDim.x;
    for (int idx = blockIdx.x * blockDim.x + threadIdx.x; idx < total; idx += stride) {
        int n = idx / C4, c = idx % C4;
        const float4* inrow = (const float4*)(in + (size_t)n * HF);
        float4 acc = make_float4(0.f, 0.f, 0.f, 0.f);
#pragma unroll 6
        for (int k4 = 0; k4 < C4; ++k4) {
            float4 a4 = inrow[k4];
            if (applyBN) {
                float4 al = sAl[k4], be = sBe[k4];
                a4.x = fmaxf(fmaf(a4.x, al.x, be.x), 0.f);
                a4.y = fmaxf(fmaf(a4.y, al.y, be.y), 0.f);
                a4.z = fmaxf(fmaf(a4.z, al.z, be.z), 0.f);
                a4.w = fmaxf(fmaf(a4.w, al.w, be.w), 0.f);
            }
            float4 w0 = sW[(k4 * 4 + 0) * C4 + c];
            float4 w1 = sW[(k4 * 4 + 1) * C4 + c];
            float4 w2 = sW[(k4 * 4 + 2) * C4 + c];
            float4 w3 = sW[(k4 * 4 + 3) * C4 + c];
            acc.x = fmaf(a4.x, w0.x, fmaf(a4.y, w1.x, fmaf(a4.z, w2.x, fmaf(a4.w, w3.x, acc.x))));
            acc.y = fmaf(a4.x, w0.y, fmaf(a4.y, w1.y, fmaf(a4.z, w2.y, fmaf(a4.w, w3.y, acc.y))));
            acc.z = fmaf(a4.x, w0.z, fmaf(a4.y, w1.z, fmaf(a4.z, w2.z, fmaf(a4.w, w3.z, acc.z))));
            acc.w = fmaf(a4.x, w0.w, fmaf(a4.y, w1.w, fmaf(a4.z, w2.w, fmaf(a4.w, w3.w, acc.w))));
        }
        ((float4*)(out + (size_t)n * HF))[c] = acc;
    }
}

// ---------------- per-layer: edge aggregation (+ BN stats accumulation) ----------------

__global__ __launch_bounds__(256) void
agg_kernel(const float* __restrict__ Hb, float* __restrict__ out,
           const int* __restrict__ row_ptr, const int* __restrict__ csr_src,
           const float* __restrict__ csr_w, const float* __restrict__ selfw,
           const float* __restrict__ convB, int N, double* __restrict__ bnsum) {
    __shared__ float sred[2 * HF];
    bool stats = (bnsum != nullptr);
    for (int i = threadIdx.x; i < 2 * HF; i += blockDim.x) sred[i] = 0.f;
    __syncthreads();
    const float4* h4 = (const float4*)Hb;
    int total = N * C4;
    int stride = gridDim.x * blockDim.x;
    for (int idx = blockIdx.x * blockDim.x + threadIdx.x; idx < total; idx += stride) {
        int n = idx / C4, c = idx % C4;
        int p0 = row_ptr[n], p1 = row_ptr[n + 1];
        float sw = selfw[n];
        float4 hn = h4[(size_t)n * C4 + c];
        float4 bb = ((const float4*)convB)[c];
        float4 acc;
        acc.x = fmaf(sw, hn.x, bb.x);
        acc.y = fmaf(sw, hn.y, bb.y);
        acc.z = fmaf(sw, hn.z, bb.z);
        acc.w = fmaf(sw, hn.w, bb.w);
        for (int p = p0; p < p1; ++p) {
            int s = csr_src[p];
            float w = csr_w[p];
            float4 hv = h4[(size_t)s * C4 + c];
            acc.x = fmaf(w, hv.x, acc.x);
            acc.y = fmaf(w, hv.y, acc.y);
            acc.z = fmaf(w, hv.z, acc.z);
            acc.w = fmaf(w, hv.w, acc.w);
        }
        ((float4*)out)[idx] = acc;
        if (stats) {
            atomicAdd(&sred[4 * c + 0], acc.x);
            atomicAdd(&sred[4 * c + 1], acc.y);
            atomicAdd(&sred[4 * c + 2], acc.z);
            atomicAdd(&sred[4 * c + 3], acc.w);
            atomicAdd(&sred[HF + 4 * c + 0], acc.x * acc.x);
            atomicAdd(&sred[HF + 4 * c + 1], acc.y * acc.y);
            atomicAdd(&sred[HF + 4 * c + 2], acc.z * acc.z);
            atomicAdd(&sred[HF + 4 * c + 3], acc.w * acc.w);
        }
    }
    if (stats) {
        __syncthreads();
        for (int i = threadIdx.x; i < 2 * HF; i += blockDim.x)
            atomicAdd(&bnsum[i], (double)sred[i]);
    }
}

// ---------------- pooling + head ----------------

__global__ void pool_kernel(const float* __restrict__ xin, const int* __restrict__ batch,
                            float* __restrict__ pooled, int N) {
    int total = N * C4;
    int stride = gridDim.x * blockDim.x;
    for (int idx = blockIdx.x * blockDim.x + threadIdx.x; idx < total; idx += stride) {
        int n = idx / C4, c = idx % C4;
        int g = batch[n];
        float4 v = ((const float4*)xin)[idx];
        atomicAdd(&pooled[g * HF + 4 * c + 0], v.x);
        atomicAdd(&pooled[g * HF + 4 * c + 1], v.y);
        atomicAdd(&pooled[g * HF + 4 * c + 2], v.z);
        atomicAdd(&pooled[g * HF + 4 * c + 3], v.w);
    }
}

__global__ void head1_kernel(const float* __restrict__ pooled, const int* __restrict__ gcnt,
                             const float* __restrict__ W1, const float* __restrict__ b1,
                             float* __restrict__ tmp1, double* __restrict__ bnsum) {
    __shared__ float row[HF];
    int g = blockIdx.x;
    float inv = 1.0f / fmaxf((float)gcnt[g], 1.0f);
    if (threadIdx.x < HF) row[threadIdx.x] = pooled[g * HF + threadIdx.x] * inv;
    __syncthreads();
    if (threadIdx.x < HF) {
        int f = threadIdx.x;
        float acc = b1[f];
        for (int k = 0; k < HF; ++k) acc = fmaf(row[k], W1[k * HF + f], acc);
        tmp1[g * HF + f] = acc;
        atomicAdd(&bnsum[f], (double)acc);
        atomicAdd(&bnsum[HF + f], (double)(acc * acc));
    }
}

__global__ void head2_kernel(const float* __restrict__ tmp1, const double* __restrict__ bnsum,
                             const float* __restrict__ g1, const float* __restrict__ be1,
                             const float* __restrict__ W2, const float* __restrict__ b2,
                             float* __restrict__ tmp2) {
    __shared__ float row[HF];
    int g = blockIdx.x;
    if (threadIdx.x < HF) {
        int f = threadIdx.x;
        double mu = bnsum[f] / (double)NGRAPHS;
        double var = bnsum[HF + f] / (double)NGRAPHS - mu * mu;
        float v = fmaxf((float)var, 0.f) + EPS;
        float a = g1[f] / sqrtf(v);
        float bb = be1[f] - (float)mu * a;
        row[f] = fmaxf(fmaf(tmp1[g * HF + f], a, bb), 0.f);
    }
    __syncthreads();
    if (threadIdx.x < HF) {
        int f = threadIdx.x;
        float acc = b2[f];
        for (int k = 0; k < HF; ++k) acc = fmaf(row[k], W2[k * HF + f], acc);
        tmp2[g * HF + f] = fmaxf(acc, 0.f);
    }
}

__global__ void head3_kernel(const float* __restrict__ tmp2, const float* __restrict__ W3,
                             const float* __restrict__ b3, float* __restrict__ out) {
    __shared__ float row[HF];
    int g = blockIdx.x;
    for (int i = threadIdx.x; i < HF; i += blockDim.x) row[i] = tmp2[g * HF + i];
    __syncthreads();
    if (threadIdx.x < 10) {
        int f = threadIdx.x;
        float acc = b3[f];
        for (int k = 0; k < HF; ++k) acc = fmaf(row[k], W3[k * 10 + f], acc);
        out[g * 10 + f] = acc;
    }
}

// ---------------- launch ----------------

extern "C" void kernel_launch(void* const* d_in, const int* in_sizes, int n_in,
                              void* d_out, int out_size, void* d_ws, size_t ws_size,
                              hipStream_t stream) {
    (void)n_in; (void)out_size; (void)ws_size;
    const float* x     = (const float*)d_in[0];
    const int*   ei    = (const int*)d_in[1];
    const int*   batch = (const int*)d_in[2];
    const float* convW = (const float*)d_in[3];
    const float* convB = (const float*)d_in[4];
    const float* bnG   = (const float*)d_in[5];
    const float* bnB   = (const float*)d_in[6];
    const float* W1    = (const float*)d_in[7];
    const float* b1    = (const float*)d_in[8];
    const float* g1    = (const float*)d_in[9];
    const float* be1   = (const float*)d_in[10];
    const float* W2    = (const float*)d_in[11];
    const float* b2    = (const float*)d_in[12];
    const float* W3    = (const float*)d_in[13];
    const float* b3    = (const float*)d_in[14];
    float* outp = (float*)d_out;

    int N = in_sizes[0] / HF;
    int E = in_sizes[1] / 2;
    const int* src  = ei;
    const int* dstp = ei + E;

    char* ws = (char*)d_ws;
    size_t off = 0;
    auto alloc = [&](size_t bytes) -> char* {
        char* p = ws + off;
        off += (bytes + 255) & ~(size_t)255;
        return p;
    };
    float* Hb      = (float*)alloc((size_t)N * HF * 4);
    float* Ob      = (float*)alloc((size_t)N * HF * 4);
    int*   csr_src = (int*)alloc((size_t)E * 4);
    float* csr_w   = (float*)alloc((size_t)E * 4);
    int*   row_ptr = (int*)alloc((size_t)(N + 1) * 4);
    float* dinv    = (float*)alloc((size_t)N * 4);
    float* selfw   = (float*)alloc((size_t)N * 4);
    char* zstart   = ws + off;
    int*    cnt    = (int*)alloc((size_t)N * 4);
    int*    gcnt   = (int*)alloc(512 * 4);
    double* bns    = (double*)alloc(6 * 2 * HF * 8);   // 5 conv BN + 1 head BN
    float*  pooled = (float*)alloc(NGRAPHS * HF * 4);
    size_t zbytes  = (size_t)((ws + off) - zstart);
    float* tmp1    = (float*)alloc(NGRAPHS * HF * 4);
    float* tmp2    = (float*)alloc(NGRAPHS * HF * 4);

    hipMemsetAsync(zstart, 0, zbytes, stream);

    count_kernel<<<1024, 256, 0, stream>>>(dstp, E, cnt);
    node_init_kernel<<<(N + 255) / 256, 256, 0, stream>>>(cnt, batch, N, dinv, selfw, gcnt);
    scan_kernel<<<1, 1024, 0, stream>>>(cnt, row_ptr, N);
    scatter_kernel<<<1024, 256, 0, stream>>>(src, dstp, E, row_ptr, cnt, dinv, csr_src, csr_w);

    const float* cur = x;
    for (int i = 0; i < 6; ++i) {
        matmul_kernel<<<960, 256, 0, stream>>>(
            cur, convW + (size_t)i * HF * HF, Hb, N,
            (i > 0) ? 1 : 0,
            (i > 0) ? bns + (size_t)(i - 1) * 2 * HF : nullptr,
            (i > 0) ? bnG + (size_t)(i - 1) * HF : nullptr,
            (i > 0) ? bnB + (size_t)(i - 1) * HF : nullptr);
        agg_kernel<<<2048, 256, 0, stream>>>(
            Hb, Ob, row_ptr, csr_src, csr_w, selfw,
            convB + (size_t)i * HF, N,
            (i < 5) ? bns + (size_t)i * 2 * HF : nullptr);
        cur = Ob;
    }

    pool_kernel<<<2048, 256, 0, stream>>>(Ob, batch, pooled, N);
    head1_kernel<<<NGRAPHS, 128, 0, stream>>>(pooled, gcnt, W1, b1, tmp1, bns + 5 * 2 * HF);
    head2_kernel<<<NGRAPHS, 128, 0, stream>>>(tmp1, bns + 5 * 2 * HF, g1, be1, W2, b2, tmp2);
    head3_kernel<<<NGRAPHS, 64, 0, stream>>>(tmp2, W3, b3, outp);
}

// Round 3
// 973.003 us; speedup vs baseline: 1.2139x; 1.2139x over previous
//
#include <hip/hip_runtime.h>

#define HF 96
#define C4 24          // float4 chunks per row
#define NGRAPHS 500
#define EPS 1e-5f

// ---------------- CSR build ----------------

__global__ void count_kernel(const int* __restrict__ dst, int E, int* __restrict__ cnt) {
    int stride = gridDim.x * blockDim.x;
    for (int i = blockIdx.x * blockDim.x + threadIdx.x; i < E; i += stride)
        atomicAdd(&cnt[dst[i]], 1);
}

__global__ void node_init_kernel(const int* __restrict__ cnt, int N,
                                 float* __restrict__ dinv, float* __restrict__ selfw) {
    int stride = gridDim.x * blockDim.x;
    for (int i = blockIdx.x * blockDim.x + threadIdx.x; i < N; i += stride) {
        float d = (float)(cnt[i] + 1);      // +1 self loop
        dinv[i] = 1.0f / sqrtf(d);
        selfw[i] = 1.0f / d;
    }
}

// 3-phase parallel scan over cnt -> row_ptr (exclusive), then zero cnt.
__global__ void scan1_kernel(const int* __restrict__ cnt, int N, int* __restrict__ bsum) {
    __shared__ int s[256];
    int t = threadIdx.x;
    int i = blockIdx.x * 256 + t;
    s[t] = (i < N) ? cnt[i] : 0;
    __syncthreads();
    for (int off = 128; off; off >>= 1) {
        if (t < off) s[t] += s[t + off];
        __syncthreads();
    }
    if (t == 0) bsum[blockIdx.x] = s[0];
}

__global__ void scan2_kernel(const int* __restrict__ bsum, int NB,
                             int* __restrict__ boff, int* __restrict__ row_ptr, int N) {
    __shared__ int s[256];
    int t = threadIdx.x;
    int v = (t < NB) ? bsum[t] : 0;
    s[t] = v;
    __syncthreads();
    for (int off = 1; off < 256; off <<= 1) {
        int u = (t >= off) ? s[t - off] : 0;
        __syncthreads();
        s[t] += u;
        __syncthreads();
    }
    if (t < NB) boff[t] = s[t] - v;   // exclusive block offset
    if (t == 255) row_ptr[N] = s[255];
}

__global__ void scan3_kernel(int* __restrict__ cnt, int N, const int* __restrict__ boff,
                             int* __restrict__ row_ptr) {
    __shared__ int s[256];
    int t = threadIdx.x;
    int i = blockIdx.x * 256 + t;
    int v = (i < N) ? cnt[i] : 0;
    s[t] = v;
    __syncthreads();
    for (int off = 1; off < 256; off <<= 1) {
        int u = (t >= off) ? s[t - off] : 0;
        __syncthreads();
        s[t] += u;
        __syncthreads();
    }
    if (i < N) {
        row_ptr[i] = boff[blockIdx.x] + s[t] - v;   // exclusive
        cnt[i] = 0;                                  // re-zero for scatter phase
    }
}

__global__ void scatter_kernel(const int* __restrict__ src, const int* __restrict__ dst, int E,
                               const int* __restrict__ row_ptr, int* __restrict__ cnt,
                               const float* __restrict__ dinv,
                               int* __restrict__ csr_src, float* __restrict__ csr_w) {
    int stride = gridDim.x * blockDim.x;
    for (int i = blockIdx.x * blockDim.x + threadIdx.x; i < E; i += stride) {
        int d = dst[i], s = src[i];
        int p = row_ptr[d] + atomicAdd(&cnt[d], 1);
        csr_src[p] = s;
        csr_w[p] = dinv[s] * dinv[d];
    }
}

// ---------------- per-layer: matmul (with fused BN+ReLU of previous layer) ----------------

__global__ __launch_bounds__(256) void
matmul_kernel(const float* __restrict__ in, const float* __restrict__ W,
              float* __restrict__ out, int N, int applyBN,
              const double* __restrict__ bnsum,
              const float* __restrict__ bnG, const float* __restrict__ bnB) {
    __shared__ float4 sW[HF * C4];           // 36 KB: W[k][4c..4c+3]
    __shared__ float4 sAl[C4], sBe[C4];
    for (int i = threadIdx.x; i < HF * C4; i += blockDim.x)
        sW[i] = ((const float4*)W)[i];
    if (threadIdx.x < HF) {
        float a = 1.f, b = 0.f;
        if (applyBN) {
            double invN = 1.0 / (double)N;
            double mu = bnsum[threadIdx.x] * invN;
            double var = bnsum[HF + threadIdx.x] * invN - mu * mu;
            float v = fmaxf((float)var, 0.f) + EPS;
            a = bnG[threadIdx.x] / sqrtf(v);
            b = bnB[threadIdx.x] - (float)mu * a;
        }
        ((float*)sAl)[threadIdx.x] = a;
        ((float*)sBe)[threadIdx.x] = b;
    }
    __syncthreads();
    int total = N * C4;
    int stride = gridDim.x * blockDim.x;
    for (int idx = blockIdx.x * blockDim.x + threadIdx.x; idx < total; idx += stride) {
        int n = idx / C4, c = idx % C4;
        const float4* inrow = (const float4*)(in + (size_t)n * HF);
        float4 acc = make_float4(0.f, 0.f, 0.f, 0.f);
#pragma unroll 6
        for (int k4 = 0; k4 < C4; ++k4) {
            float4 a4 = inrow[k4];
            if (applyBN) {
                float4 al = sAl[k4], be = sBe[k4];
                a4.x = fmaxf(fmaf(a4.x, al.x, be.x), 0.f);
                a4.y = fmaxf(fmaf(a4.y, al.y, be.y), 0.f);
                a4.z = fmaxf(fmaf(a4.z, al.z, be.z), 0.f);
                a4.w = fmaxf(fmaf(a4.w, al.w, be.w), 0.f);
            }
            float4 w0 = sW[(k4 * 4 + 0) * C4 + c];
            float4 w1 = sW[(k4 * 4 + 1) * C4 + c];
            float4 w2 = sW[(k4 * 4 + 2) * C4 + c];
            float4 w3 = sW[(k4 * 4 + 3) * C4 + c];
            acc.x = fmaf(a4.x, w0.x, fmaf(a4.y, w1.x, fmaf(a4.z, w2.x, fmaf(a4.w, w3.x, acc.x))));
            acc.y = fmaf(a4.x, w0.y, fmaf(a4.y, w1.y, fmaf(a4.z, w2.y, fmaf(a4.w, w3.y, acc.y))));
            acc.z = fmaf(a4.x, w0.z, fmaf(a4.y, w1.z, fmaf(a4.z, w2.z, fmaf(a4.w, w3.z, acc.z))));
            acc.w = fmaf(a4.x, w0.w, fmaf(a4.y, w1.w, fmaf(a4.z, w2.w, fmaf(a4.w, w3.w, acc.w))));
        }
        ((float4*)(out + (size_t)n * HF))[c] = acc;
    }
}

// ---------------- per-layer: edge aggregation (+ BN stats accumulation) ----------------

__global__ __launch_bounds__(256) void
agg_kernel(const float* __restrict__ Hb, float* __restrict__ out,
           const int* __restrict__ row_ptr, const int* __restrict__ csr_src,
           const float* __restrict__ csr_w, const float* __restrict__ selfw,
           const float* __restrict__ convB, int N, double* __restrict__ bnsum) {
    __shared__ float sred[2 * HF];
    bool stats = (bnsum != nullptr);
    for (int i = threadIdx.x; i < 2 * HF; i += blockDim.x) sred[i] = 0.f;
    __syncthreads();
    const float4* h4 = (const float4*)Hb;
    int total = N * C4;
    int stride = gridDim.x * blockDim.x;
    for (int idx = blockIdx.x * blockDim.x + threadIdx.x; idx < total; idx += stride) {
        int n = idx / C4, c = idx % C4;
        int p0 = row_ptr[n], p1 = row_ptr[n + 1];
        float sw = selfw[n];
        float4 hn = h4[(size_t)n * C4 + c];
        float4 bb = ((const float4*)convB)[c];
        float4 acc;
        acc.x = fmaf(sw, hn.x, bb.x);
        acc.y = fmaf(sw, hn.y, bb.y);
        acc.z = fmaf(sw, hn.z, bb.z);
        acc.w = fmaf(sw, hn.w, bb.w);
        for (int p = p0; p < p1; ++p) {
            int s = csr_src[p];
            float w = csr_w[p];
            float4 hv = h4[(size_t)s * C4 + c];
            acc.x = fmaf(w, hv.x, acc.x);
            acc.y = fmaf(w, hv.y, acc.y);
            acc.z = fmaf(w, hv.z, acc.z);
            acc.w = fmaf(w, hv.w, acc.w);
        }
        ((float4*)out)[idx] = acc;
        if (stats) {
            atomicAdd(&sred[4 * c + 0], acc.x);
            atomicAdd(&sred[4 * c + 1], acc.y);
            atomicAdd(&sred[4 * c + 2], acc.z);
            atomicAdd(&sred[4 * c + 3], acc.w);
            atomicAdd(&sred[HF + 4 * c + 0], acc.x * acc.x);
            atomicAdd(&sred[HF + 4 * c + 1], acc.y * acc.y);
            atomicAdd(&sred[HF + 4 * c + 2], acc.z * acc.z);
            atomicAdd(&sred[HF + 4 * c + 3], acc.w * acc.w);
        }
    }
    if (stats) {
        __syncthreads();
        for (int i = threadIdx.x; i < 2 * HF; i += blockDim.x)
            atomicAdd(&bnsum[i], (double)sred[i]);
    }
}

// ---------------- pooling + head (fused) ----------------

// One block per graph. batch is sorted -> binary search segment bounds.
__global__ __launch_bounds__(128) void
pool_head1_kernel(const float* __restrict__ xin, const int* __restrict__ batch, int N,
                  const float* __restrict__ W1, const float* __restrict__ b1,
                  float* __restrict__ tmp1, double* __restrict__ bnsum) {
    __shared__ float row[HF];
    int g = blockIdx.x;
    int lo = 0, hi = N;
    while (lo < hi) { int m = (lo + hi) >> 1; if (batch[m] < g) lo = m + 1; else hi = m; }
    int s0 = lo;
    lo = s0; hi = N;
    while (lo < hi) { int m = (lo + hi) >> 1; if (batch[m] < g + 1) lo = m + 1; else hi = m; }
    int s1 = lo;
    int f = threadIdx.x;
    if (f < HF) {
        float sum = 0.f;
        for (int n = s0; n < s1; ++n) sum += xin[(size_t)n * HF + f];
        float inv = 1.0f / fmaxf((float)(s1 - s0), 1.0f);
        row[f] = sum * inv;
    }
    __syncthreads();
    if (f < HF) {
        float acc = b1[f];
        for (int k = 0; k < HF; ++k) acc = fmaf(row[k], W1[k * HF + f], acc);
        tmp1[g * HF + f] = acc;
        atomicAdd(&bnsum[f], (double)acc);
        atomicAdd(&bnsum[HF + f], (double)(acc * acc));
    }
}

__global__ __launch_bounds__(128) void
head23_kernel(const float* __restrict__ tmp1, const double* __restrict__ bnsum,
              const float* __restrict__ g1, const float* __restrict__ be1,
              const float* __restrict__ W2, const float* __restrict__ b2,
              const float* __restrict__ W3, const float* __restrict__ b3,
              float* __restrict__ out) {
    __shared__ float row[HF], row2[HF];
    int g = blockIdx.x;
    int f = threadIdx.x;
    if (f < HF) {
        double mu = bnsum[f] / (double)NGRAPHS;
        double var = bnsum[HF + f] / (double)NGRAPHS - mu * mu;
        float v = fmaxf((float)var, 0.f) + EPS;
        float a = g1[f] / sqrtf(v);
        float bb = be1[f] - (float)mu * a;
        row[f] = fmaxf(fmaf(tmp1[g * HF + f], a, bb), 0.f);
    }
    __syncthreads();
    if (f < HF) {
        float acc = b2[f];
        for (int k = 0; k < HF; ++k) acc = fmaf(row[k], W2[k * HF + f], acc);
        row2[f] = fmaxf(acc, 0.f);
    }
    __syncthreads();
    if (f < 10) {
        float acc = b3[f];
        for (int k = 0; k < HF; ++k) acc = fmaf(row2[k], W3[k * 10 + f], acc);
        out[g * 10 + f] = acc;
    }
}

// ---------------- launch ----------------

extern "C" void kernel_launch(void* const* d_in, const int* in_sizes, int n_in,
                              void* d_out, int out_size, void* d_ws, size_t ws_size,
                              hipStream_t stream) {
    (void)n_in; (void)out_size; (void)ws_size;
    const float* x     = (const float*)d_in[0];
    const int*   ei    = (const int*)d_in[1];
    const int*   batch = (const int*)d_in[2];
    const float* convW = (const float*)d_in[3];
    const float* convB = (const float*)d_in[4];
    const float* bnG   = (const float*)d_in[5];
    const float* bnB   = (const float*)d_in[6];
    const float* W1    = (const float*)d_in[7];
    const float* b1    = (const float*)d_in[8];
    const float* g1    = (const float*)d_in[9];
    const float* be1   = (const float*)d_in[10];
    const float* W2    = (const float*)d_in[11];
    const float* b2    = (const float*)d_in[12];
    const float* W3    = (const float*)d_in[13];
    const float* b3    = (const float*)d_in[14];
    float* outp = (float*)d_out;

    int N = in_sizes[0] / HF;
    int E = in_sizes[1] / 2;
    int NB = (N + 255) / 256;
    const int* src  = ei;
    const int* dstp = ei + E;

    char* ws = (char*)d_ws;
    size_t off = 0;
    auto alloc = [&](size_t bytes) -> char* {
        char* p = ws + off;
        off += (bytes + 255) & ~(size_t)255;
        return p;
    };
    float* Hb      = (float*)alloc((size_t)N * HF * 4);
    float* Ob      = (float*)alloc((size_t)N * HF * 4);
    int*   csr_src = (int*)alloc((size_t)E * 4);
    float* csr_w   = (float*)alloc((size_t)E * 4);
    int*   row_ptr = (int*)alloc((size_t)(N + 1) * 4);
    float* dinv    = (float*)alloc((size_t)N * 4);
    float* selfw   = (float*)alloc((size_t)N * 4);
    int*   bsum    = (int*)alloc((size_t)NB * 4);
    int*   boff    = (int*)alloc((size_t)NB * 4);
    float* tmp1    = (float*)alloc((size_t)NGRAPHS * HF * 4);
    char* zstart   = ws + off;
    int*    cnt    = (int*)alloc((size_t)N * 4);
    double* bns    = (double*)alloc(6 * 2 * HF * 8);   // 5 conv BN + 1 head BN
    size_t zbytes  = (size_t)((ws + off) - zstart);

    hipMemsetAsync(zstart, 0, zbytes, stream);

    count_kernel<<<1024, 256, 0, stream>>>(dstp, E, cnt);
    node_init_kernel<<<(N + 255) / 256, 256, 0, stream>>>(cnt, N, dinv, selfw);
    scan1_kernel<<<NB, 256, 0, stream>>>(cnt, N, bsum);
    scan2_kernel<<<1, 256, 0, stream>>>(bsum, NB, boff, row_ptr, N);
    scan3_kernel<<<NB, 256, 0, stream>>>(cnt, N, boff, row_ptr);
    scatter_kernel<<<1024, 256, 0, stream>>>(src, dstp, E, row_ptr, cnt, dinv, csr_src, csr_w);

    const float* cur = x;
    for (int i = 0; i < 6; ++i) {
        matmul_kernel<<<960, 256, 0, stream>>>(
            cur, convW + (size_t)i * HF * HF, Hb, N,
            (i > 0) ? 1 : 0,
            (i > 0) ? bns + (size_t)(i - 1) * 2 * HF : nullptr,
            (i > 0) ? bnG + (size_t)(i - 1) * HF : nullptr,
            (i > 0) ? bnB + (size_t)(i - 1) * HF : nullptr);
        agg_kernel<<<2048, 256, 0, stream>>>(
            Hb, Ob, row_ptr, csr_src, csr_w, selfw,
            convB + (size_t)i * HF, N,
            (i < 5) ? bns + (size_t)i * 2 * HF : nullptr);
        cur = Ob;
    }

    pool_head1_kernel<<<NGRAPHS, 128, 0, stream>>>(Ob, batch, N, W1, b1, tmp1, bns + 5 * 2 * HF);
    head23_kernel<<<NGRAPHS, 128, 0, stream>>>(tmp1, bns + 5 * 2 * HF, g1, be1, W2, b2, W3, b3, outp);
}

// Round 4
// 832.234 us; speedup vs baseline: 1.4192x; 1.1691x over previous
//
#include <hip/hip_runtime.h>
#include <hip/hip_fp16.h>

#define HF 96
#define C4 24          // float4 chunks per f32 row
#define CH 12          // uint4 (8-half) chunks per f16 row
#define NGRAPHS 500
#define EPS 1e-5f

__device__ __forceinline__ float4 h4tof4(uint2 u) {
    __half2 a = *(__half2*)&u.x;
    __half2 b = *(__half2*)&u.y;
    float2 fa = __half22float2(a);
    float2 fb = __half22float2(b);
    return make_float4(fa.x, fa.y, fb.x, fb.y);
}

// ---------------- CSR build ----------------

__global__ void count_kernel(const int* __restrict__ dst, int E, int* __restrict__ cnt) {
    int stride = gridDim.x * blockDim.x;
    for (int i = blockIdx.x * blockDim.x + threadIdx.x; i < E; i += stride)
        atomicAdd(&cnt[dst[i]], 1);
}

__global__ void node_init_kernel(const int* __restrict__ cnt, int N,
                                 float* __restrict__ dinv, float* __restrict__ selfw) {
    int stride = gridDim.x * blockDim.x;
    for (int i = blockIdx.x * blockDim.x + threadIdx.x; i < N; i += stride) {
        float d = (float)(cnt[i] + 1);      // +1 self loop
        dinv[i] = 1.0f / sqrtf(d);
        selfw[i] = 1.0f / d;
    }
}

__global__ void scan1_kernel(const int* __restrict__ cnt, int N, int* __restrict__ bsum) {
    __shared__ int s[256];
    int t = threadIdx.x;
    int i = blockIdx.x * 256 + t;
    s[t] = (i < N) ? cnt[i] : 0;
    __syncthreads();
    for (int off = 128; off; off >>= 1) {
        if (t < off) s[t] += s[t + off];
        __syncthreads();
    }
    if (t == 0) bsum[blockIdx.x] = s[0];
}

__global__ void scan2_kernel(const int* __restrict__ bsum, int NB,
                             int* __restrict__ boff, int* __restrict__ row_ptr, int N) {
    __shared__ int s[256];
    int t = threadIdx.x;
    int v = (t < NB) ? bsum[t] : 0;
    s[t] = v;
    __syncthreads();
    for (int off = 1; off < 256; off <<= 1) {
        int u = (t >= off) ? s[t - off] : 0;
        __syncthreads();
        s[t] += u;
        __syncthreads();
    }
    if (t < NB) boff[t] = s[t] - v;
    if (t == 255) row_ptr[N] = s[255];
}

__global__ void scan3_kernel(int* __restrict__ cnt, int N, const int* __restrict__ boff,
                             int* __restrict__ row_ptr) {
    __shared__ int s[256];
    int t = threadIdx.x;
    int i = blockIdx.x * 256 + t;
    int v = (i < N) ? cnt[i] : 0;
    s[t] = v;
    __syncthreads();
    for (int off = 1; off < 256; off <<= 1) {
        int u = (t >= off) ? s[t - off] : 0;
        __syncthreads();
        s[t] += u;
        __syncthreads();
    }
    if (i < N) {
        row_ptr[i] = boff[blockIdx.x] + s[t] - v;
        cnt[i] = 0;
    }
}

__global__ void scatter_kernel(const int* __restrict__ src, const int* __restrict__ dst, int E,
                               const int* __restrict__ row_ptr, int* __restrict__ cnt,
                               const float* __restrict__ dinv,
                               int2* __restrict__ csr) {
    int stride = gridDim.x * blockDim.x;
    for (int i = blockIdx.x * blockDim.x + threadIdx.x; i < E; i += stride) {
        int d = dst[i], s = src[i];
        int p = row_ptr[d] + atomicAdd(&cnt[d], 1);
        float w = dinv[s] * dinv[d];
        csr[p] = make_int2(s, __float_as_int(w));
    }
}

// ---------------- per-layer: matmul (fused BN+ReLU of prev layer), f16 output ----------------

__global__ __launch_bounds__(256) void
matmul_kernel(const float* __restrict__ in, const float* __restrict__ W,
              __half* __restrict__ out, int N, int applyBN,
              const double* __restrict__ bnsum,
              const float* __restrict__ bnG, const float* __restrict__ bnB) {
    __shared__ float4 sW[HF * C4];           // 36 KB: W[k][4c..4c+3]
    __shared__ float4 sAl[C4], sBe[C4];
    for (int i = threadIdx.x; i < HF * C4; i += blockDim.x)
        sW[i] = ((const float4*)W)[i];
    if (threadIdx.x < HF) {
        float a = 1.f, b = 0.f;
        if (applyBN) {
            double invN = 1.0 / (double)N;
            double mu = bnsum[threadIdx.x] * invN;
            double var = bnsum[HF + threadIdx.x] * invN - mu * mu;
            float v = fmaxf((float)var, 0.f) + EPS;
            a = bnG[threadIdx.x] / sqrtf(v);
            b = bnB[threadIdx.x] - (float)mu * a;
        }
        ((float*)sAl)[threadIdx.x] = a;
        ((float*)sBe)[threadIdx.x] = b;
    }
    __syncthreads();
    int nG = (N + 3) >> 2;                   // 4-node register tile
    int total = nG * C4;
    int stride = gridDim.x * blockDim.x;
    for (int idx = blockIdx.x * blockDim.x + threadIdx.x; idx < total; idx += stride) {
        int ng = idx / C4, c = idx % C4;
        int n0 = ng * 4;
        int rem = N - n0;                    // >=1
        const float4* r0 = (const float4*)(in + (size_t)n0 * HF);
        const float4* r1 = r0 + ((rem > 1) ? C4 : 0);
        const float4* r2 = r0 + ((rem > 2) ? 2 * C4 : 0);
        const float4* r3 = r0 + ((rem > 3) ? 3 * C4 : 0);
        float4 acc0 = make_float4(0.f, 0.f, 0.f, 0.f);
        float4 acc1 = acc0, acc2 = acc0, acc3 = acc0;
#pragma unroll 4
        for (int k4 = 0; k4 < C4; ++k4) {
            float4 al = sAl[k4], be = sBe[k4];
            float4 w0 = sW[(k4 * 4 + 0) * C4 + c];
            float4 w1 = sW[(k4 * 4 + 1) * C4 + c];
            float4 w2 = sW[(k4 * 4 + 2) * C4 + c];
            float4 w3 = sW[(k4 * 4 + 3) * C4 + c];
            float4 a0 = r0[k4], a1 = r1[k4], a2 = r2[k4], a3 = r3[k4];
            if (applyBN) {
                a0.x = fmaxf(fmaf(a0.x, al.x, be.x), 0.f); a0.y = fmaxf(fmaf(a0.y, al.y, be.y), 0.f);
                a0.z = fmaxf(fmaf(a0.z, al.z, be.z), 0.f); a0.w = fmaxf(fmaf(a0.w, al.w, be.w), 0.f);
                a1.x = fmaxf(fmaf(a1.x, al.x, be.x), 0.f); a1.y = fmaxf(fmaf(a1.y, al.y, be.y), 0.f);
                a1.z = fmaxf(fmaf(a1.z, al.z, be.z), 0.f); a1.w = fmaxf(fmaf(a1.w, al.w, be.w), 0.f);
                a2.x = fmaxf(fmaf(a2.x, al.x, be.x), 0.f); a2.y = fmaxf(fmaf(a2.y, al.y, be.y), 0.f);
                a2.z = fmaxf(fmaf(a2.z, al.z, be.z), 0.f); a2.w = fmaxf(fmaf(a2.w, al.w, be.w), 0.f);
                a3.x = fmaxf(fmaf(a3.x, al.x, be.x), 0.f); a3.y = fmaxf(fmaf(a3.y, al.y, be.y), 0.f);
                a3.z = fmaxf(fmaf(a3.z, al.z, be.z), 0.f); a3.w = fmaxf(fmaf(a3.w, al.w, be.w), 0.f);
            }
#define ACC(ACCV, AV) \
            ACCV.x = fmaf(AV.x, w0.x, fmaf(AV.y, w1.x, fmaf(AV.z, w2.x, fmaf(AV.w, w3.x, ACCV.x)))); \
            ACCV.y = fmaf(AV.x, w0.y, fmaf(AV.y, w1.y, fmaf(AV.z, w2.y, fmaf(AV.w, w3.y, ACCV.y)))); \
            ACCV.z = fmaf(AV.x, w0.z, fmaf(AV.y, w1.z, fmaf(AV.z, w2.z, fmaf(AV.w, w3.z, ACCV.z)))); \
            ACCV.w = fmaf(AV.x, w0.w, fmaf(AV.y, w1.w, fmaf(AV.z, w2.w, fmaf(AV.w, w3.w, ACCV.w))));
            ACC(acc0, a0) ACC(acc1, a1) ACC(acc2, a2) ACC(acc3, a3)
#undef ACC
        }
        uint2* orow = (uint2*)out;
#define STORE(J, ACCV) \
        if (rem > J) { \
            __half2 lo = __floats2half2_rn(ACCV.x, ACCV.y); \
            __half2 hi = __floats2half2_rn(ACCV.z, ACCV.w); \
            orow[(size_t)(n0 + J) * C4 + c] = make_uint2(*(unsigned int*)&lo, *(unsigned int*)&hi); \
        }
        STORE(0, acc0) STORE(1, acc1) STORE(2, acc2) STORE(3, acc3)
#undef STORE
    }
}

// ---------------- per-layer: edge aggregation (+ BN stats), f16 gathers ----------------

__global__ __launch_bounds__(256) void
agg_kernel(const __half* __restrict__ Hb, float* __restrict__ out,
           const int* __restrict__ row_ptr, const int2* __restrict__ csr,
           const float* __restrict__ selfw, const float* __restrict__ convB,
           int N, double* __restrict__ bnsum) {
    __shared__ float sred[2 * HF];
    bool stats = (bnsum != nullptr);
    for (int i = threadIdx.x; i < 2 * HF; i += blockDim.x) sred[i] = 0.f;
    __syncthreads();
    const uint4* h4p = (const uint4*)Hb;     // row = CH uint4 chunks of 8 halfs
    int total = N * CH;
    int stride = gridDim.x * blockDim.x;
    for (int idx = blockIdx.x * blockDim.x + threadIdx.x; idx < total; idx += stride) {
        int n = idx / CH, c = idx % CH;
        int p0 = row_ptr[n], p1 = row_ptr[n + 1];
        float sw = selfw[n];
        uint4 hraw = h4p[(size_t)n * CH + c];
        float4 hlo = h4tof4(make_uint2(hraw.x, hraw.y));
        float4 hhi = h4tof4(make_uint2(hraw.z, hraw.w));
        float4 blo = ((const float4*)convB)[2 * c];
        float4 bhi = ((const float4*)convB)[2 * c + 1];
        float4 alo, ahi;
        alo.x = fmaf(sw, hlo.x, blo.x); alo.y = fmaf(sw, hlo.y, blo.y);
        alo.z = fmaf(sw, hlo.z, blo.z); alo.w = fmaf(sw, hlo.w, blo.w);
        ahi.x = fmaf(sw, hhi.x, bhi.x); ahi.y = fmaf(sw, hhi.y, bhi.y);
        ahi.z = fmaf(sw, hhi.z, bhi.z); ahi.w = fmaf(sw, hhi.w, bhi.w);
#define EDGE(EV, RV) { \
            float w = __int_as_float(EV.y); \
            float4 vlo = h4tof4(make_uint2(RV.x, RV.y)); \
            float4 vhi = h4tof4(make_uint2(RV.z, RV.w)); \
            alo.x = fmaf(w, vlo.x, alo.x); alo.y = fmaf(w, vlo.y, alo.y); \
            alo.z = fmaf(w, vlo.z, alo.z); alo.w = fmaf(w, vlo.w, alo.w); \
            ahi.x = fmaf(w, vhi.x, ahi.x); ahi.y = fmaf(w, vhi.y, ahi.y); \
            ahi.z = fmaf(w, vhi.z, ahi.z); ahi.w = fmaf(w, vhi.w, ahi.w); }
        int p = p0;
        for (; p + 4 <= p1; p += 4) {
            int2 e0 = csr[p], e1 = csr[p + 1], e2 = csr[p + 2], e3 = csr[p + 3];
            uint4 g0 = h4p[(size_t)e0.x * CH + c];
            uint4 g1 = h4p[(size_t)e1.x * CH + c];
            uint4 g2 = h4p[(size_t)e2.x * CH + c];
            uint4 g3 = h4p[(size_t)e3.x * CH + c];
            EDGE(e0, g0) EDGE(e1, g1) EDGE(e2, g2) EDGE(e3, g3)
        }
        for (; p < p1; ++p) {
            int2 e = csr[p];
            uint4 g = h4p[(size_t)e.x * CH + c];
            EDGE(e, g)
        }
#undef EDGE
        ((float4*)out)[2 * idx]     = alo;
        ((float4*)out)[2 * idx + 1] = ahi;
        if (stats) {
            int f = 8 * c;
            atomicAdd(&sred[f + 0], alo.x); atomicAdd(&sred[f + 1], alo.y);
            atomicAdd(&sred[f + 2], alo.z); atomicAdd(&sred[f + 3], alo.w);
            atomicAdd(&sred[f + 4], ahi.x); atomicAdd(&sred[f + 5], ahi.y);
            atomicAdd(&sred[f + 6], ahi.z); atomicAdd(&sred[f + 7], ahi.w);
            atomicAdd(&sred[HF + f + 0], alo.x * alo.x); atomicAdd(&sred[HF + f + 1], alo.y * alo.y);
            atomicAdd(&sred[HF + f + 2], alo.z * alo.z); atomicAdd(&sred[HF + f + 3], alo.w * alo.w);
            atomicAdd(&sred[HF + f + 4], ahi.x * ahi.x); atomicAdd(&sred[HF + f + 5], ahi.y * ahi.y);
            atomicAdd(&sred[HF + f + 6], ahi.z * ahi.z); atomicAdd(&sred[HF + f + 7], ahi.w * ahi.w);
        }
    }
    if (stats) {
        __syncthreads();
        for (int i = threadIdx.x; i < 2 * HF; i += blockDim.x)
            atomicAdd(&bnsum[i], (double)sred[i]);
    }
}

// ---------------- pooling + head (fused) ----------------

__global__ __launch_bounds__(128) void
pool_head1_kernel(const float* __restrict__ xin, const int* __restrict__ batch, int N,
                  const float* __restrict__ W1, const float* __restrict__ b1,
                  float* __restrict__ tmp1, double* __restrict__ bnsum) {
    __shared__ float row[HF];
    int g = blockIdx.x;
    int lo = 0, hi = N;
    while (lo < hi) { int m = (lo + hi) >> 1; if (batch[m] < g) lo = m + 1; else hi = m; }
    int s0 = lo;
    lo = s0; hi = N;
    while (lo < hi) { int m = (lo + hi) >> 1; if (batch[m] < g + 1) lo = m + 1; else hi = m; }
    int s1 = lo;
    int f = threadIdx.x;
    if (f < HF) {
        float sum = 0.f;
        for (int n = s0; n < s1; ++n) sum += xin[(size_t)n * HF + f];
        float inv = 1.0f / fmaxf((float)(s1 - s0), 1.0f);
        row[f] = sum * inv;
    }
    __syncthreads();
    if (f < HF) {
        float acc = b1[f];
        for (int k = 0; k < HF; ++k) acc = fmaf(row[k], W1[k * HF + f], acc);
        tmp1[g * HF + f] = acc;
        atomicAdd(&bnsum[f], (double)acc);
        atomicAdd(&bnsum[HF + f], (double)(acc * acc));
    }
}

__global__ __launch_bounds__(128) void
head23_kernel(const float* __restrict__ tmp1, const double* __restrict__ bnsum,
              const float* __restrict__ g1, const float* __restrict__ be1,
              const float* __restrict__ W2, const float* __restrict__ b2,
              const float* __restrict__ W3, const float* __restrict__ b3,
              float* __restrict__ out) {
    __shared__ float row[HF], row2[HF];
    int g = blockIdx.x;
    int f = threadIdx.x;
    if (f < HF) {
        double mu = bnsum[f] / (double)NGRAPHS;
        double var = bnsum[HF + f] / (double)NGRAPHS - mu * mu;
        float v = fmaxf((float)var, 0.f) + EPS;
        float a = g1[f] / sqrtf(v);
        float bb = be1[f] - (float)mu * a;
        row[f] = fmaxf(fmaf(tmp1[g * HF + f], a, bb), 0.f);
    }
    __syncthreads();
    if (f < HF) {
        float acc = b2[f];
        for (int k = 0; k < HF; ++k) acc = fmaf(row[k], W2[k * HF + f], acc);
        row2[f] = fmaxf(acc, 0.f);
    }
    __syncthreads();
    if (f < 10) {
        float acc = b3[f];
        for (int k = 0; k < HF; ++k) acc = fmaf(row2[k], W3[k * 10 + f], acc);
        out[g * 10 + f] = acc;
    }
}

// ---------------- launch ----------------

extern "C" void kernel_launch(void* const* d_in, const int* in_sizes, int n_in,
                              void* d_out, int out_size, void* d_ws, size_t ws_size,
                              hipStream_t stream) {
    (void)n_in; (void)out_size; (void)ws_size;
    const float* x     = (const float*)d_in[0];
    const int*   ei    = (const int*)d_in[1];
    const int*   batch = (const int*)d_in[2];
    const float* convW = (const float*)d_in[3];
    const float* convB = (const float*)d_in[4];
    const float* bnG   = (const float*)d_in[5];
    const float* bnB   = (const float*)d_in[6];
    const float* W1    = (const float*)d_in[7];
    const float* b1    = (const float*)d_in[8];
    const float* g1    = (const float*)d_in[9];
    const float* be1   = (const float*)d_in[10];
    const float* W2    = (const float*)d_in[11];
    const float* b2    = (const float*)d_in[12];
    const float* W3    = (const float*)d_in[13];
    const float* b3    = (const float*)d_in[14];
    float* outp = (float*)d_out;

    int N = in_sizes[0] / HF;
    int E = in_sizes[1] / 2;
    int NB = (N + 255) / 256;
    const int* src  = ei;
    const int* dstp = ei + E;

    char* ws = (char*)d_ws;
    size_t off = 0;
    auto alloc = [&](size_t bytes) -> char* {
        char* p = ws + off;
        off += (bytes + 255) & ~(size_t)255;
        return p;
    };
    __half* Hb     = (__half*)alloc((size_t)N * HF * 2);
    float* Ob      = (float*)alloc((size_t)N * HF * 4);
    int2*  csr     = (int2*)alloc((size_t)E * 8);
    int*   row_ptr = (int*)alloc((size_t)(N + 1) * 4);
    float* dinv    = (float*)alloc((size_t)N * 4);
    float* selfw   = (float*)alloc((size_t)N * 4);
    int*   bsum    = (int*)alloc((size_t)NB * 4);
    int*   boff    = (int*)alloc((size_t)NB * 4);
    float* tmp1    = (float*)alloc((size_t)NGRAPHS * HF * 4);
    char* zstart   = ws + off;
    int*    cnt    = (int*)alloc((size_t)N * 4);
    double* bns    = (double*)alloc(6 * 2 * HF * 8);   // 5 conv BN + 1 head BN
    size_t zbytes  = (size_t)((ws + off) - zstart);

    hipMemsetAsync(zstart, 0, zbytes, stream);

    count_kernel<<<1024, 256, 0, stream>>>(dstp, E, cnt);
    node_init_kernel<<<(N + 255) / 256, 256, 0, stream>>>(cnt, N, dinv, selfw);
    scan1_kernel<<<NB, 256, 0, stream>>>(cnt, N, bsum);
    scan2_kernel<<<1, 256, 0, stream>>>(bsum, NB, boff, row_ptr, N);
    scan3_kernel<<<NB, 256, 0, stream>>>(cnt, N, boff, row_ptr);
    scatter_kernel<<<1024, 256, 0, stream>>>(src, dstp, E, row_ptr, cnt, dinv, csr);

    const float* cur = x;
    for (int i = 0; i < 6; ++i) {
        int nG = (N + 3) >> 2;
        int mm_grid = (nG * C4 + 255) / 256;
        matmul_kernel<<<mm_grid, 256, 0, stream>>>(
            cur, convW + (size_t)i * HF * HF, Hb, N,
            (i > 0) ? 1 : 0,
            (i > 0) ? bns + (size_t)(i - 1) * 2 * HF : nullptr,
            (i > 0) ? bnG + (size_t)(i - 1) * HF : nullptr,
            (i > 0) ? bnB + (size_t)(i - 1) * HF : nullptr);
        agg_kernel<<<2048, 256, 0, stream>>>(
            Hb, Ob, row_ptr, csr, selfw,
            convB + (size_t)i * HF, N,
            (i < 5) ? bns + (size_t)i * 2 * HF : nullptr);
        cur = Ob;
    }

    pool_head1_kernel<<<NGRAPHS, 128, 0, stream>>>(Ob, batch, N, W1, b1, tmp1, bns + 5 * 2 * HF);
    head23_kernel<<<NGRAPHS, 128, 0, stream>>>(tmp1, bns + 5 * 2 * HF, g1, be1, W2, b2, W3, b3, outp);
}